// Round 1
// baseline (89.475 us; speedup 1.0000x reference)
//
#include <hip/hip_runtime.h>

typedef float v2f __attribute__((ext_vector_type(2)));

#define LOG2E 1.4426950408889634f

__device__ __forceinline__ float fast_exp2(float x) {
#if __has_builtin(__builtin_amdgcn_exp2f)
    return __builtin_amdgcn_exp2f(x);
#else
    return exp2f(x);
#endif
}

__device__ __forceinline__ v2f pk_fma(v2f a, v2f b, v2f c) {
    return __builtin_elementwise_fma(a, b, c);
}

// v4: one THREAD per w (256 threads == W), one block per (b,h) row.
//
// vs v3 (4 waves split the u-range, partial-combine epilogue):
//  - each lane owns a complete output element -> NO cross-wave partial
//    combine, no 12KB partial LDS, no second barrier, no wave0-only
//    epilogue where 3/4 of the block idles.
//  - live state drops from ~70+ VGPRs (4 w's of packed accumulators) to
//    ~35 -> __launch_bounds__(256, 8): 32 waves/CU, and the 2048-block
//    grid is a SINGLE tranche (8 blocks/CU * 256 CU = 2048). v3 ran two
//    tranches at 16 waves/CU; the exp->sum dependency chain was
//    latency-exposed at that occupancy (measured 89.8us vs ~11us
//    issue-bound floor).
//  - softmax shift: with no additive combining across waves, the shift
//    only needs uniformity over u for a FIXED w -> per-lane bound
//    c = |q[w]| * sqrt(max_u |k[u]|^2) (Cauchy-Schwarz). Only k^2 needs
//    a block reduction.
//
// Main loop per lane: 128 u-pairs, each {2x ds_read_b128 broadcast
// (wave-uniform index -> conflict-free), 4 pk_fma, 1 pk_add, 2 v_exp_f32}.
__global__ __launch_bounds__(256, 8) void csa_kernel(
    const float* __restrict__ x1, const float* __restrict__ x2,
    const float* __restrict__ wq, const float* __restrict__ bq,
    const float* __restrict__ wk, const float* __restrict__ bk,
    const float* __restrict__ wv, const float* __restrict__ bv,
    float* __restrict__ out1, float* __restrict__ out2)
{
    constexpr int W = 256;
    __shared__ float4 sK[W / 2];   // (k0[u0],k0[u1],k1[u0],k1[u1]) per u-pair
    __shared__ float4 sV[W / 2];   // (v0[u0],v0[u1],v1[u0],v1[u1])
    __shared__ float red[4];       // per-wave k2 max

    const int t = threadIdx.x;     // == w
    const int wid = t >> 6;
    const int l = t & 63;
    const long base = (long)blockIdx.x * W;

    // coalesced dword loads: lane t covers w = t
    const float X1 = x1[base + t];
    const float X2 = x2[base + t];

    const float wq00 = wq[0], wq01 = wq[1], wq10 = wq[2], wq11 = wq[3];
    const float wk00 = wk[0], wk01 = wk[1], wk10 = wk[2], wk11 = wk[3];
    const float wv00 = wv[0], wv01 = wv[1], wv10 = wv[2], wv11 = wv[3];
    const float bq0 = bq[0], bq1 = bq[1];
    const float bk0 = bk[0], bk1 = bk[1];
    const float bv0 = bv[0], bv1 = bv[1];

    const float q0 = fmaf(wq00, X1, fmaf(wq01, X2, bq0));
    const float q1 = fmaf(wq10, X1, fmaf(wq11, X2, bq1));
    const float k0 = fmaf(wk00, X1, fmaf(wk01, X2, bk0));
    const float k1 = fmaf(wk10, X1, fmaf(wk11, X2, bk1));
    const float v0 = fmaf(wv00, X1, fmaf(wv01, X2, bv0));
    const float v1 = fmaf(wv10, X1, fmaf(wv11, X2, bv1));

    // stage pair-packed K/V: thread t = (up = t>>1, i = t&1)
    // one-time scatter, worst 4-way bank alias on 4 scalar writes.
    {
        float* sKf = (float*)sK;
        float* sVf = (float*)sV;
        const int up = t >> 1, i = t & 1;
        sKf[4 * up + i]     = k0;
        sKf[4 * up + 2 + i] = k1;
        sVf[4 * up + i]     = v0;
        sVf[4 * up + 2 + i] = v1;
    }

    // block max of |k|^2 (the only cross-wave reduction left)
    float k2 = fmaf(k0, k0, k1 * k1);
#pragma unroll
    for (int off = 32; off >= 1; off >>= 1)
        k2 = fmaxf(k2, __shfl_xor(k2, off, 64));
    if (l == 0) red[wid] = k2;
    __syncthreads();
    const float k2m = fmaxf(fmaxf(red[0], red[1]), fmaxf(red[2], red[3]));

    // per-lane Cauchy-Schwarz shift: c >= max_u |q[w].k[u]|
    const float q2 = fmaf(q0, q0, q1 * q1);
    const float csh = -sqrtf(q2 * k2m) * LOG2E;
    const v2f cshv = {csh, csh};
    const float a0 = q0 * LOG2E, a1 = q1 * LOG2E;
    const v2f ql0 = {a0, a0};
    const v2f ql1 = {a1, a1};

    v2f sum = {0.f, 0.f}, o0 = {0.f, 0.f}, o1 = {0.f, 0.f};

#pragma unroll 4
    for (int u = 0; u < W / 2; ++u) {
        const float4 K = sK[u];     // wave-uniform addr -> broadcast
        const float4 V = sV[u];
        const v2f kx = {K.x, K.y};
        const v2f kz = {K.z, K.w};
        const v2f vx = {V.x, V.y};
        const v2f vz = {V.z, V.w};
        v2f s = pk_fma(ql0, kx, pk_fma(ql1, kz, cshv));
        v2f e;
        e.x = fast_exp2(s.x);
        e.y = fast_exp2(s.y);
        sum += e;
        o0 = pk_fma(e, vx, o0);
        o1 = pk_fma(e, vz, o1);
    }

    const float S = sum.x + sum.y;
    const float inv = 1.0f / S;
    out1[base + t] = fmaf(o0.x + o0.y, inv, X1);
    out2[base + t] = fmaf(o1.x + o1.y, inv, X2);
}

extern "C" void kernel_launch(void* const* d_in, const int* in_sizes, int n_in,
                              void* d_out, int out_size, void* d_ws, size_t ws_size,
                              hipStream_t stream) {
    const float* x1 = (const float*)d_in[0];
    const float* x2 = (const float*)d_in[1];
    const float* wq = (const float*)d_in[2];
    const float* bq = (const float*)d_in[3];
    const float* wk = (const float*)d_in[4];
    const float* bk = (const float*)d_in[5];
    const float* wv = (const float*)d_in[6];
    const float* bv = (const float*)d_in[7];

    float* out = (float*)d_out;
    const int BHW = in_sizes[0];            // 4*512*256 = 524288
    const int rows = BHW / 256;             // B*H = 2048

    csa_kernel<<<rows, 256, 0, stream>>>(x1, x2, wq, bq, wk, bk, wv, bv,
                                         out, out + BHW);
}